// Round 19
// baseline (155.482 us; speedup 1.0000x reference)
//
#include <hip/hip_runtime.h>

#define IN_CH 128
#define OUT_CH 64
#define MAXBKT 256      // 512 nodes per bucket -> supports N <= 131072
#define BKT_SH 9
#define BKT_MSK 511
#define CAPB   9216     // per-bucket true-edge capacity (avg 8192 @ E=1.6M, 11-sigma margin)
#define CAPB_PAD 16896  // padded stride: CAPB + 512 nodes * 15 max pad
#define CHUNK  13312    // edges per binning block (121 blocks -> 4x less reservation contention)

typedef __attribute__((ext_vector_type(8))) short short8v;   // 8 bf16 (4 VGPRs)
typedef __attribute__((ext_vector_type(4))) float float4v;   // 4 fp32 acc

union Pack { short8v s8; unsigned u[4]; };

__device__ __forceinline__ unsigned short f2bf(float f) {   // RNE float->bf16
    unsigned u = __float_as_uint(f);
    return (unsigned short)((u + 0x7fffu + ((u >> 16) & 1u)) >> 16);
}
__device__ __forceinline__ unsigned pk2(float a, float b) { // two bf16 in a dword (a=lo)
    return ((unsigned)f2bf(b) << 16) | (unsigned)f2bf(a);
}
__device__ __forceinline__ float bflo(unsigned d) { return __uint_as_float(d << 16); }
__device__ __forceinline__ float bfhi(unsigned d) { return __uint_as_float(d & 0xffff0000u); }

// ---------------- zero bucket counters (d_ws NOT re-poisoned between replays) ----------------
__global__ void k_zero_cnt(unsigned* __restrict__ cnt, int n) {
    int i = blockIdx.x * blockDim.x + threadIdx.x;
    if (i < n) cnt[i] = 0u;
}

// ============ FUSED: blocks [0,nBin) bin edges; blocks [nBin, nBin+nChunks) do GEMM ============
// binA: big chunks (121 blocks) -> short same-address reservation-atomic queues; col re-read from L2.
// gemm: one 64-row chunk per block, W staged via LDS, hs UNSCALED (dinv applied in csrB post-pass).
__global__ __launch_bounds__(256) void k_AG(const float* __restrict__ x,
                                            const float* __restrict__ W,
                                            const int* __restrict__ ei,
                                            unsigned* __restrict__ bucketCount,
                                            unsigned* __restrict__ binned,
                                            unsigned short* __restrict__ hs,
                                            int N, int E, int nbkt, int nBin) {
    __shared__ float smem[IN_CH * 66];   // 33.8 KB, aliased by both paths
    int tid = threadIdx.x;

    if (blockIdx.x < nBin) {
        // ---------------- binA path ----------------
        unsigned* hist = (unsigned*)smem;          // [MAXBKT]
        unsigned* resv = hist + MAXBKT;            // [MAXBKT]
        int start = blockIdx.x * CHUNK;
        int end = start + CHUNK; if (end > E) end = E;
        int cnt = end - start;

        for (int i = tid; i < MAXBKT; i += 256) hist[i] = 0u;
        __syncthreads();

        for (int i = tid; i < cnt; i += 256) {
            int c = ei[E + start + i];
            atomicAdd(&hist[c >> BKT_SH], 1u);
        }
        __syncthreads();

        if (tid < nbkt) {
            resv[tid] = atomicAdd(&bucketCount[tid], hist[tid]);   // 121-deep queue per address
            hist[tid] = 0u;   // reuse as local rank cursor
        }
        __syncthreads();

        for (int i = tid; i < cnt; i += 256) {
            int c = ei[E + start + i];             // L2-hot re-read (no colS stage at this CHUNK)
            int r = ei[start + i];
            int bkt = c >> BKT_SH;
            unsigned rank = atomicAdd(&hist[bkt], 1u);
            unsigned idx = resv[bkt] + rank;
            if (idx < CAPB)
                binned[(size_t)bkt * CAPB + idx] = ((unsigned)r << BKT_SH) | (unsigned)(c & BKT_MSK);
        }
    } else {
        // ---------------- gemm path ----------------
        int chunk = blockIdx.x - nBin;
        int wid = tid >> 6;
        int l   = tid & 63;
        int g   = l >> 4;
        int m   = l & 15;

        if (chunk == 0 && tid < 32)   // zero the dummy row hs[N] (gather pad target)
            ((unsigned*)hs)[((size_t)N << 5) + tid] = 0u;

        float* Wl = smem;             // [128][66], stride 66 breaks bank alias
        const float4* W4 = (const float4*)W;
#pragma unroll
        for (int j = 0; j < 8; ++j) {
            int i4 = tid + j * 256;
            float4 w = W4[i4];
            int i = i4 * 4;
            int k = i >> 6, c = i & 63;
            float* dst = Wl + k * 66 + c;
            dst[0] = w.x; dst[1] = w.y; dst[2] = w.z; dst[3] = w.w;
        }
        __syncthreads();

        short8v bf[4][4];
#pragma unroll
        for (int s = 0; s < 4; ++s)
#pragma unroll
            for (int t = 0; t < 4; ++t) {
                Pack p;
#pragma unroll
                for (int jj = 0; jj < 4; ++jj) {
                    int k = s * 32 + g * 8 + 2 * jj;
                    float f0 = Wl[(k + 0) * 66 + t * 16 + m];
                    float f1 = Wl[(k + 1) * 66 + t * 16 + m];
                    p.u[jj] = pk2(f0, f1);
                }
                bf[s][t] = p.s8;
            }

        int R0 = chunk * 64 + wid * 16;
        int rowA = R0 + m; if (rowA > N - 1) rowA = N - 1;
        float4v acc[4];
#pragma unroll
        for (int t = 0; t < 4; ++t) acc[t] = (float4v){0.f, 0.f, 0.f, 0.f};

        const float4* x4 = (const float4*)x;
#pragma unroll
        for (int s = 0; s < 4; ++s) {
            const float4* ap = x4 + (size_t)rowA * 32 + s * 8 + g * 2;
            float4 a0 = ap[0];
            float4 a1 = ap[1];
            Pack pa;
            pa.u[0] = pk2(a0.x, a0.y);
            pa.u[1] = pk2(a0.z, a0.w);
            pa.u[2] = pk2(a1.x, a1.y);
            pa.u[3] = pk2(a1.z, a1.w);
#pragma unroll
            for (int t = 0; t < 4; ++t)
                acc[t] = __builtin_amdgcn_mfma_f32_16x16x32_bf16(pa.s8, bf[s][t], acc[t], 0, 0, 0);
        }

        int rbase = R0 + g * 4;
#pragma unroll
        for (int r = 0; r < 4; ++r) {
            int row = rbase + r;
            if (row < N) {
#pragma unroll
                for (int t = 0; t < 4; ++t)
                    hs[(size_t)row * OUT_CH + t * 16 + m] = f2bf(acc[t][r]);
            }
        }
    }
}

// ---------------- Phase B: padded CSR build + hs dinv-scaling post-pass ----------------
__global__ __launch_bounds__(1024) void k_csrB(const unsigned* __restrict__ binned,
                                               const unsigned* __restrict__ bucketCount,
                                               int* __restrict__ rows,
                                               unsigned* __restrict__ offs,
                                               unsigned* __restrict__ degPad,
                                               float* __restrict__ dinv,
                                               unsigned short* __restrict__ hs,
                                               int N, int nbkt) {
    __shared__ unsigned hist[512];
    __shared__ unsigned degS[512];
    __shared__ unsigned excl[512];
    __shared__ unsigned wsum[8];
    __shared__ unsigned wexc[8];
    __shared__ unsigned stage[CAPB];   // 36 KB
    int tid = threadIdx.x;
    int b = blockIdx.x;
    unsigned cnt = bucketCount[b];
    if (cnt > (unsigned)CAPB) cnt = (unsigned)CAPB;
    size_t gbase = (size_t)b * CAPB_PAD;
    int nodeBase = b << BKT_SH;
    int nn = N - nodeBase; if (nn > 512) nn = 512;

    for (int i = tid; i < 512; i += 1024) hist[i] = 0u;
    __syncthreads();                                   // B1

    const unsigned* src = binned + (size_t)b * CAPB;
    for (unsigned i = tid; i < cnt; i += 1024) {
        unsigned p = src[i];
        stage[i] = p;
        atomicAdd(&hist[p & BKT_MSK], 1u);
    }
    __syncthreads();                                   // B2

    // exclusive scan of padded degrees: wave-shfl scan (threads 0..511 = waves 0..7)
    unsigned d = 0, dp = 0, winc = 0;
    if (tid < 512) {
        d = hist[tid];
        degS[tid] = d;                                 // save true degree
        dp = (d + 15u) & ~15u;
        winc = dp;
#pragma unroll
        for (int o = 1; o < 64; o <<= 1) {
            unsigned t = __shfl_up(winc, o);
            if ((tid & 63) >= o) winc += t;
        }
        if ((tid & 63) == 63) wsum[tid >> 6] = winc;
    }
    __syncthreads();                                   // B3
    if (tid < 8) {
        unsigned s = wsum[tid];
        unsigned inc = s;
#pragma unroll
        for (int o = 1; o < 8; o <<= 1) {
            unsigned t = __shfl_up(inc, o);
            if (tid >= o) inc += t;
        }
        wexc[tid] = inc - s;
    }
    __syncthreads();                                   // B4
    if (tid < 512) excl[tid] = wexc[tid >> 6] + winc - dp;
    __syncthreads();                                   // B5

    if (tid < nn) {
        offs[nodeBase + tid]   = (unsigned)gbase + excl[tid];
        degPad[nodeBase + tid] = dp;
        dinv[nodeBase + tid]   = rsqrtf((float)d + 1.0f);
    }

    // reverse-rank scatter: first writer gets slot d-1, last gets 0
    for (unsigned i = tid; i < cnt; i += 1024) {
        unsigned p = stage[i];
        unsigned c = p & BKT_MSK;
        unsigned r = atomicAdd(&hist[c], 0xFFFFFFFFu);   // returns old count
        rows[gbase + excl[c] + r - 1u] = (int)(p >> BKT_SH);
    }
    // pad fill [d, dp): disjoint from scatter range [0, d)
    if (tid < nn) {
        size_t base = gbase + excl[tid];
        for (unsigned p = d; p < dp; ++p) rows[base + p] = N;
    }

    // ---- post-pass: hs[row] *= dinv(row) for this bucket's rows (2 threads/row) ----
    int node_l = tid >> 1;
    if (node_l < nn) {
        float dv = rsqrtf((float)degS[node_l] + 1.0f);
        uint4* hq = (uint4*)hs;
        size_t base = ((size_t)(nodeBase + node_l) << 3) + ((size_t)(tid & 1) << 2);
#pragma unroll
        for (int q = 0; q < 4; ++q) {
            uint4 w = hq[base + q];
            w.x = pk2(bflo(w.x) * dv, bfhi(w.x) * dv);
            w.y = pk2(bflo(w.y) * dv, bfhi(w.y) * dv);
            w.z = pk2(bflo(w.z) * dv, bfhi(w.z) * dv);
            w.w = pk2(bflo(w.w) * dv, bfhi(w.w) * dv);
            hq[base + q] = w;
        }
    }
}

// ---------------- wave-per-node gather: padded lists, mask-free 8-deep rounds ----------------
__global__ __launch_bounds__(256) void k_gather(const unsigned* __restrict__ offs,
                                                const unsigned* __restrict__ degPad,
                                                const int* __restrict__ rows,
                                                const unsigned* __restrict__ hsd,
                                                const float* __restrict__ dinv,
                                                const float* __restrict__ b,
                                                const float* __restrict__ Wc,
                                                float* __restrict__ u,
                                                float* __restrict__ v, int n) {
    int lane = threadIdx.x & 63;
    int half = lane >> 5;          // 0 or 1
    int l32  = lane & 31;
    int node = blockIdx.x * (blockDim.x >> 6) + (threadIdx.x >> 6);
    if (node >= n) return;
    unsigned start = offs[node];
    unsigned cntP = degPad[node];              // multiple of 16 (possibly 0)
    const int* rp = rows + start;

    unsigned ds = hsd[((size_t)node << 5) + l32];
    float acc0 = half ? 0.f : bflo(ds);        // self-loop: half 0 only
    float acc1 = half ? 0.f : bfhi(ds);

    for (unsigned j0 = 0; j0 < cntP; j0 += 64) {
        unsigned rem = cntP - j0;
        unsigned np = rem < 64u ? rem : 64u;   // multiple of 16, wave-uniform
        int myidx = rp[j0 + (lane < (int)np ? lane : 0)];   // one coalesced load / window

        for (unsigned t0 = 0; t0 < np; t0 += 16) {   // 16 edges, 8 gathers in flight / half
            int rr[8];
#pragma unroll
            for (int s = 0; s < 8; ++s)
                rr[s] = __shfl(myidx, (int)t0 + 2 * s + half);
            unsigned dd[8];
#pragma unroll
            for (int s = 0; s < 8; ++s)
                dd[s] = hsd[((size_t)rr[s] << 5) + l32];
#pragma unroll
            for (int s = 0; s < 8; ++s) {
                acc0 += bflo(dd[s]);
                acc1 += bfhi(dd[s]);
            }
        }
    }

    acc0 += __shfl_xor(acc0, 32);              // both halves now hold the full sums
    acc1 += __shfl_xor(acc1, 32);

    float di = dinv[node];
    float2 bv = ((const float2*)b)[l32];
    float z0 = fmaxf(fmaf(acc0, di, bv.x), 0.f);
    float z1 = fmaxf(fmaf(acc1, di, bv.y), 0.f);

    // split epilogue: half 0 reduces u (Wc[:64]), half 1 reduces v (Wc[64:])
    float4 w = ((const float4*)(Wc + (half ? 128 : 0)))[l32];
    float p0 = z0 * w.x + z1 * w.z;
    float p1 = z0 * w.y + z1 * w.w;
#pragma unroll
    for (int off = 16; off > 0; off >>= 1) {   // xor-butterfly stays within each 32-half
        p0 += __shfl_xor(p0, off);
        p1 += __shfl_xor(p1, off);
    }
    float2 r; r.x = p0; r.y = p1;
    if (lane == 0)  ((float2*)u)[node] = r;
    if (lane == 32) ((float2*)v)[node] = r;
}

// ---------------- out: 4 edges per thread, int4 index loads, 2x float4 stores ----------------
__global__ void k_edges(const int* __restrict__ ei, const int* __restrict__ nei,
                        const float* __restrict__ u, const float* __restrict__ v,
                        const float* __restrict__ bc, float* __restrict__ out, int E) {
    int i = blockIdx.x * blockDim.x + threadIdx.x;   // quad index; E % 4 == 0
    int quads = E >> 1;                              // total quads over pos+neg (2E/4)
    if (i >= quads) return;
    int halfQ = quads >> 1;                          // E/4 pos quads
    const int* base = (i < halfQ) ? ei : nei;
    int pi = (i < halfQ) ? i : i - halfQ;
    int4 ss = ((const int4*)base)[pi];
    int4 dd = ((const int4*)(base + E))[pi];
    float2 u0 = ((const float2*)u)[ss.x];
    float2 u1 = ((const float2*)u)[ss.y];
    float2 u2 = ((const float2*)u)[ss.z];
    float2 u3 = ((const float2*)u)[ss.w];
    float2 v0 = ((const float2*)v)[dd.x];
    float2 v1 = ((const float2*)v)[dd.y];
    float2 v2 = ((const float2*)v)[dd.z];
    float2 v3 = ((const float2*)v)[dd.w];
    float b0 = bc[0], b1 = bc[1];
    float4 r0, r1;
    r0.x = u0.x + v0.x + b0;  r0.y = u0.y + v0.y + b1;
    r0.z = u1.x + v1.x + b0;  r0.w = u1.y + v1.y + b1;
    r1.x = u2.x + v2.x + b0;  r1.y = u2.y + v2.y + b1;
    r1.z = u3.x + v3.x + b0;  r1.w = u3.y + v3.y + b1;
    ((float4*)out)[2 * i + 0] = r0;
    ((float4*)out)[2 * i + 1] = r1;
}

extern "C" void kernel_launch(void* const* d_in, const int* in_sizes, int n_in,
                              void* d_out, int out_size, void* d_ws, size_t ws_size,
                              hipStream_t stream) {
    const float* x   = (const float*)d_in[0];
    const int*   ei  = (const int*)d_in[1];
    const int*   nei = (const int*)d_in[2];
    const float* W   = (const float*)d_in[3];
    const float* b   = (const float*)d_in[4];
    const float* Wc  = (const float*)d_in[5];
    const float* bc  = (const float*)d_in[6];
    float* out = (float*)d_out;

    const int N = in_sizes[0] / IN_CH;        // 100000
    const int E = in_sizes[1] / 2;            // 1600000
    const int nbkt = (N + BKT_MSK) >> BKT_SH; // 196
    const int nChunks = (N + 63) / 64;        // 1563
    const int nBin = (E + CHUNK - 1) / CHUNK; // 121

    char* ws = (char*)d_ws;
    size_t off = 0;
    unsigned short* hs = (unsigned short*)(ws + off); off += ((size_t)N + 1) * OUT_CH * 2; // 12.8 MB + dummy row
    unsigned* binned = (unsigned*)(ws + off); off += (size_t)MAXBKT * CAPB * 4;            // 9.4 MB
    int*      rows   = (int*)(ws + off);      off += (size_t)MAXBKT * CAPB_PAD * 4;        // 17.3 MB
    unsigned* offs   = (unsigned*)(ws + off); off += (size_t)N * 4;
    unsigned* degP   = (unsigned*)(ws + off); off += (size_t)N * 4;
    float*    dinv   = (float*)(ws + off);    off += (size_t)N * 4;
    float*    u      = (float*)(ws + off);    off += (size_t)N * 2 * 4;
    float*    v      = (float*)(ws + off);    off += (size_t)N * 2 * 4;
    unsigned* bucketCount = (unsigned*)(ws + off); off += (size_t)MAXBKT * 4;

    k_zero_cnt<<<1, 256, 0, stream>>>(bucketCount, MAXBKT);
    k_AG<<<nBin + nChunks, 256, 0, stream>>>(x, W, ei, bucketCount, binned, hs, N, E, nbkt, nBin);
    k_csrB<<<nbkt, 1024, 0, stream>>>(binned, bucketCount, rows, offs, degP, dinv, hs, N, nbkt);
    k_gather<<<(N + 3) / 4, 256, 0, stream>>>(offs, degP, rows, (const unsigned*)hs, dinv, b, Wc, u, v, N);
    k_edges<<<(E / 2 + 255) / 256, 256, 0, stream>>>(ei, nei, u, v, bc, out, E);
}

// Round 20
// 131.554 us; speedup vs baseline: 1.1819x; 1.1819x over previous
//
#include <hip/hip_runtime.h>

#define IN_CH 128
#define OUT_CH 64
#define MAXBKT 256      // 512 nodes per bucket -> supports N <= 131072
#define BKT_SH 9
#define BKT_MSK 511
#define CAPB   9216     // per-bucket true-edge capacity (avg 8192 @ E=1.6M, 11-sigma margin)
#define CAPB_PAD 16896  // padded stride: CAPB + 512 nodes * 15 max pad
#define BINCHUNK 4096   // edges per binning block (1024 thr x 4 edges, one vector iteration)

typedef __attribute__((ext_vector_type(8))) short short8v;   // 8 bf16 (4 VGPRs)
typedef __attribute__((ext_vector_type(4))) float float4v;   // 4 fp32 acc

union Pack { short8v s8; unsigned u[4]; };

__device__ __forceinline__ unsigned short f2bf(float f) {   // RNE float->bf16
    unsigned u = __float_as_uint(f);
    return (unsigned short)((u + 0x7fffu + ((u >> 16) & 1u)) >> 16);
}
__device__ __forceinline__ unsigned pk2(float a, float b) { // two bf16 in a dword (a=lo)
    return ((unsigned)f2bf(b) << 16) | (unsigned)f2bf(a);
}
__device__ __forceinline__ float bflo(unsigned d) { return __uint_as_float(d << 16); }
__device__ __forceinline__ float bfhi(unsigned d) { return __uint_as_float(d & 0xffff0000u); }

// ---------------- zero bucket counters (d_ws NOT re-poisoned between replays) ----------------
__global__ void k_zero_cnt(unsigned* __restrict__ cnt, int n) {
    int i = blockIdx.x * blockDim.x + threadIdx.x;
    if (i < n) cnt[i] = 0u;
}

// ============ FUSED 1024-thread: blocks [0,nBin) bin edges; [nBin, nBin+nG) do GEMM ============
// binA: 4096 edges/block, int4 edge loads (ONE vector iteration per pass), ~30 waves/CU TLP.
// gemm: 256 rows/block (16 waves), W staged via LDS, hs UNSCALED (dinv applied in csrB).
__global__ __launch_bounds__(1024) void k_AG(const float* __restrict__ x,
                                             const float* __restrict__ W,
                                             const int* __restrict__ ei,
                                             unsigned* __restrict__ bucketCount,
                                             unsigned* __restrict__ binned,
                                             unsigned short* __restrict__ hs,
                                             int N, int E, int nbkt, int nBin) {
    __shared__ float smem[IN_CH * 66];   // 33.8 KB, aliased by both paths
    int tid = threadIdx.x;

    if (blockIdx.x < nBin) {
        // ---------------- binA path ----------------
        unsigned* hist = (unsigned*)smem;          // [MAXBKT]
        unsigned* resv = hist + MAXBKT;            // [MAXBKT]
        int start = blockIdx.x * BINCHUNK;
        int cnt = E - start; if (cnt > BINCHUNK) cnt = BINCHUNK;
        int i0 = tid * 4;

        if (tid < MAXBKT) hist[tid] = 0u;
        __syncthreads();

        // pass 1: histogram (one int4 load per thread)
        if (i0 < cnt) {
            if (i0 + 4 <= cnt) {
                int4 c = ((const int4*)(ei + E + start))[tid];
                atomicAdd(&hist[c.x >> BKT_SH], 1u);
                atomicAdd(&hist[c.y >> BKT_SH], 1u);
                atomicAdd(&hist[c.z >> BKT_SH], 1u);
                atomicAdd(&hist[c.w >> BKT_SH], 1u);
            } else {
                for (int k = i0; k < cnt; ++k)
                    atomicAdd(&hist[ei[E + start + k] >> BKT_SH], 1u);
            }
        }
        __syncthreads();

        if (tid < nbkt) {
            resv[tid] = atomicAdd(&bucketCount[tid], hist[tid]);
            hist[tid] = 0u;   // reuse as local rank cursor
        }
        __syncthreads();

        // pass 2: scatter (col re-read L2-hot + row int4 load)
        if (i0 < cnt) {
            if (i0 + 4 <= cnt) {
                int4 c = ((const int4*)(ei + E + start))[tid];
                int4 r = ((const int4*)(ei + start))[tid];
                int cc[4] = {c.x, c.y, c.z, c.w};
                int rr[4] = {r.x, r.y, r.z, r.w};
#pragma unroll
                for (int k = 0; k < 4; ++k) {
                    int bkt = cc[k] >> BKT_SH;
                    unsigned rank = atomicAdd(&hist[bkt], 1u);
                    unsigned idx = resv[bkt] + rank;
                    if (idx < CAPB)
                        binned[(size_t)bkt * CAPB + idx] =
                            ((unsigned)rr[k] << BKT_SH) | (unsigned)(cc[k] & BKT_MSK);
                }
            } else {
                for (int k = i0; k < cnt; ++k) {
                    int c = ei[E + start + k];
                    int r = ei[start + k];
                    int bkt = c >> BKT_SH;
                    unsigned rank = atomicAdd(&hist[bkt], 1u);
                    unsigned idx = resv[bkt] + rank;
                    if (idx < CAPB)
                        binned[(size_t)bkt * CAPB + idx] =
                            ((unsigned)r << BKT_SH) | (unsigned)(c & BKT_MSK);
                }
            }
        }
    } else {
        // ---------------- gemm path: 256 rows per block (16 waves) ----------------
        int chunk = blockIdx.x - nBin;
        int wid = tid >> 6;    // 0..15
        int l   = tid & 63;
        int g   = l >> 4;
        int m   = l & 15;

        if (chunk == 0 && tid < 32)   // zero the dummy row hs[N] (gather pad target)
            ((unsigned*)hs)[((size_t)N << 5) + tid] = 0u;

        float* Wl = smem;             // [128][66], stride 66 breaks bank alias
        const float4* W4 = (const float4*)W;
#pragma unroll
        for (int j = 0; j < 2; ++j) {
            int i4 = tid + j * 1024;  // over 2048 float4
            float4 w = W4[i4];
            int i = i4 * 4;
            int k = i >> 6, c = i & 63;
            float* dst = Wl + k * 66 + c;
            dst[0] = w.x; dst[1] = w.y; dst[2] = w.z; dst[3] = w.w;
        }
        __syncthreads();

        short8v bf[4][4];
#pragma unroll
        for (int s = 0; s < 4; ++s)
#pragma unroll
            for (int t = 0; t < 4; ++t) {
                Pack p;
#pragma unroll
                for (int jj = 0; jj < 4; ++jj) {
                    int k = s * 32 + g * 8 + 2 * jj;
                    float f0 = Wl[(k + 0) * 66 + t * 16 + m];
                    float f1 = Wl[(k + 1) * 66 + t * 16 + m];
                    p.u[jj] = pk2(f0, f1);
                }
                bf[s][t] = p.s8;
            }

        int R0 = chunk * 256 + wid * 16;
        int rowA = R0 + m; if (rowA > N - 1) rowA = N - 1;
        float4v acc[4];
#pragma unroll
        for (int t = 0; t < 4; ++t) acc[t] = (float4v){0.f, 0.f, 0.f, 0.f};

        const float4* x4 = (const float4*)x;
#pragma unroll
        for (int s = 0; s < 4; ++s) {
            const float4* ap = x4 + (size_t)rowA * 32 + s * 8 + g * 2;
            float4 a0 = ap[0];
            float4 a1 = ap[1];
            Pack pa;
            pa.u[0] = pk2(a0.x, a0.y);
            pa.u[1] = pk2(a0.z, a0.w);
            pa.u[2] = pk2(a1.x, a1.y);
            pa.u[3] = pk2(a1.z, a1.w);
#pragma unroll
            for (int t = 0; t < 4; ++t)
                acc[t] = __builtin_amdgcn_mfma_f32_16x16x32_bf16(pa.s8, bf[s][t], acc[t], 0, 0, 0);
        }

        int rbase = R0 + g * 4;
#pragma unroll
        for (int r = 0; r < 4; ++r) {
            int row = rbase + r;
            if (row < N) {
#pragma unroll
                for (int t = 0; t < 4; ++t)
                    hs[(size_t)row * OUT_CH + t * 16 + m] = f2bf(acc[t][r]);
            }
        }
    }
}

// ---------------- Phase B: padded CSR build + hs dinv-scaling post-pass ----------------
__global__ __launch_bounds__(1024) void k_csrB(const unsigned* __restrict__ binned,
                                               const unsigned* __restrict__ bucketCount,
                                               int* __restrict__ rows,
                                               unsigned* __restrict__ offs,
                                               unsigned* __restrict__ degPad,
                                               float* __restrict__ dinv,
                                               unsigned short* __restrict__ hs,
                                               int N, int nbkt) {
    __shared__ unsigned hist[512];
    __shared__ unsigned degS[512];
    __shared__ unsigned excl[512];
    __shared__ unsigned wsum[8];
    __shared__ unsigned wexc[8];
    __shared__ unsigned stage[CAPB];   // 36 KB
    int tid = threadIdx.x;
    int b = blockIdx.x;
    unsigned cnt = bucketCount[b];
    if (cnt > (unsigned)CAPB) cnt = (unsigned)CAPB;
    size_t gbase = (size_t)b * CAPB_PAD;
    int nodeBase = b << BKT_SH;
    int nn = N - nodeBase; if (nn > 512) nn = 512;

    for (int i = tid; i < 512; i += 1024) hist[i] = 0u;
    __syncthreads();                                   // B1

    const unsigned* src = binned + (size_t)b * CAPB;
    for (unsigned i = tid; i < cnt; i += 1024) {
        unsigned p = src[i];
        stage[i] = p;
        atomicAdd(&hist[p & BKT_MSK], 1u);
    }
    __syncthreads();                                   // B2

    // exclusive scan of padded degrees: wave-shfl scan (threads 0..511 = waves 0..7)
    unsigned d = 0, dp = 0, winc = 0;
    if (tid < 512) {
        d = hist[tid];
        degS[tid] = d;                                 // save true degree
        dp = (d + 15u) & ~15u;
        winc = dp;
#pragma unroll
        for (int o = 1; o < 64; o <<= 1) {
            unsigned t = __shfl_up(winc, o);
            if ((tid & 63) >= o) winc += t;
        }
        if ((tid & 63) == 63) wsum[tid >> 6] = winc;
    }
    __syncthreads();                                   // B3
    if (tid < 8) {
        unsigned s = wsum[tid];
        unsigned inc = s;
#pragma unroll
        for (int o = 1; o < 8; o <<= 1) {
            unsigned t = __shfl_up(inc, o);
            if (tid >= o) inc += t;
        }
        wexc[tid] = inc - s;
    }
    __syncthreads();                                   // B4
    if (tid < 512) excl[tid] = wexc[tid >> 6] + winc - dp;
    __syncthreads();                                   // B5

    if (tid < nn) {
        offs[nodeBase + tid]   = (unsigned)gbase + excl[tid];
        degPad[nodeBase + tid] = dp;
        dinv[nodeBase + tid]   = rsqrtf((float)d + 1.0f);
    }

    // reverse-rank scatter: first writer gets slot d-1, last gets 0
    for (unsigned i = tid; i < cnt; i += 1024) {
        unsigned p = stage[i];
        unsigned c = p & BKT_MSK;
        unsigned r = atomicAdd(&hist[c], 0xFFFFFFFFu);   // returns old count
        rows[gbase + excl[c] + r - 1u] = (int)(p >> BKT_SH);
    }
    // pad fill [d, dp): disjoint from scatter range [0, d)
    if (tid < nn) {
        size_t base = gbase + excl[tid];
        for (unsigned p = d; p < dp; ++p) rows[base + p] = N;
    }

    // ---- post-pass: hs[row] *= dinv(row) for this bucket's rows (2 threads/row) ----
    int node_l = tid >> 1;
    if (node_l < nn) {
        float dv = rsqrtf((float)degS[node_l] + 1.0f);
        uint4* hq = (uint4*)hs;
        size_t base = ((size_t)(nodeBase + node_l) << 3) + ((size_t)(tid & 1) << 2);
#pragma unroll
        for (int q = 0; q < 4; ++q) {
            uint4 w = hq[base + q];
            w.x = pk2(bflo(w.x) * dv, bfhi(w.x) * dv);
            w.y = pk2(bflo(w.y) * dv, bfhi(w.y) * dv);
            w.z = pk2(bflo(w.z) * dv, bfhi(w.z) * dv);
            w.w = pk2(bflo(w.w) * dv, bfhi(w.w) * dv);
            hq[base + q] = w;
        }
    }
}

// ---------------- wave-per-node gather: padded lists, mask-free 8-deep rounds ----------------
__global__ __launch_bounds__(256) void k_gather(const unsigned* __restrict__ offs,
                                                const unsigned* __restrict__ degPad,
                                                const int* __restrict__ rows,
                                                const unsigned* __restrict__ hsd,
                                                const float* __restrict__ dinv,
                                                const float* __restrict__ b,
                                                const float* __restrict__ Wc,
                                                float* __restrict__ u,
                                                float* __restrict__ v, int n) {
    int lane = threadIdx.x & 63;
    int half = lane >> 5;          // 0 or 1
    int l32  = lane & 31;
    int node = blockIdx.x * (blockDim.x >> 6) + (threadIdx.x >> 6);
    if (node >= n) return;
    unsigned start = offs[node];
    unsigned cntP = degPad[node];              // multiple of 16 (possibly 0)
    const int* rp = rows + start;

    unsigned ds = hsd[((size_t)node << 5) + l32];
    float acc0 = half ? 0.f : bflo(ds);        // self-loop: half 0 only
    float acc1 = half ? 0.f : bfhi(ds);

    for (unsigned j0 = 0; j0 < cntP; j0 += 64) {
        unsigned rem = cntP - j0;
        unsigned np = rem < 64u ? rem : 64u;   // multiple of 16, wave-uniform
        int myidx = rp[j0 + (lane < (int)np ? lane : 0)];   // one coalesced load / window

        for (unsigned t0 = 0; t0 < np; t0 += 16) {   // 16 edges, 8 gathers in flight / half
            int rr[8];
#pragma unroll
            for (int s = 0; s < 8; ++s)
                rr[s] = __shfl(myidx, (int)t0 + 2 * s + half);
            unsigned dd[8];
#pragma unroll
            for (int s = 0; s < 8; ++s)
                dd[s] = hsd[((size_t)rr[s] << 5) + l32];
#pragma unroll
            for (int s = 0; s < 8; ++s) {
                acc0 += bflo(dd[s]);
                acc1 += bfhi(dd[s]);
            }
        }
    }

    acc0 += __shfl_xor(acc0, 32);              // both halves now hold the full sums
    acc1 += __shfl_xor(acc1, 32);

    float di = dinv[node];
    float2 bv = ((const float2*)b)[l32];
    float z0 = fmaxf(fmaf(acc0, di, bv.x), 0.f);
    float z1 = fmaxf(fmaf(acc1, di, bv.y), 0.f);

    // split epilogue: half 0 reduces u (Wc[:64]), half 1 reduces v (Wc[64:])
    float4 w = ((const float4*)(Wc + (half ? 128 : 0)))[l32];
    float p0 = z0 * w.x + z1 * w.z;
    float p1 = z0 * w.y + z1 * w.w;
#pragma unroll
    for (int off = 16; off > 0; off >>= 1) {   // xor-butterfly stays within each 32-half
        p0 += __shfl_xor(p0, off);
        p1 += __shfl_xor(p1, off);
    }
    float2 r; r.x = p0; r.y = p1;
    if (lane == 0)  ((float2*)u)[node] = r;
    if (lane == 32) ((float2*)v)[node] = r;
}

// ---------------- out: 4 edges per thread, int4 index loads, 2x float4 stores ----------------
__global__ void k_edges(const int* __restrict__ ei, const int* __restrict__ nei,
                        const float* __restrict__ u, const float* __restrict__ v,
                        const float* __restrict__ bc, float* __restrict__ out, int E) {
    int i = blockIdx.x * blockDim.x + threadIdx.x;   // quad index; E % 4 == 0
    int quads = E >> 1;                              // total quads over pos+neg (2E/4)
    if (i >= quads) return;
    int halfQ = quads >> 1;                          // E/4 pos quads
    const int* base = (i < halfQ) ? ei : nei;
    int pi = (i < halfQ) ? i : i - halfQ;
    int4 ss = ((const int4*)base)[pi];
    int4 dd = ((const int4*)(base + E))[pi];
    float2 u0 = ((const float2*)u)[ss.x];
    float2 u1 = ((const float2*)u)[ss.y];
    float2 u2 = ((const float2*)u)[ss.z];
    float2 u3 = ((const float2*)u)[ss.w];
    float2 v0 = ((const float2*)v)[dd.x];
    float2 v1 = ((const float2*)v)[dd.y];
    float2 v2 = ((const float2*)v)[dd.z];
    float2 v3 = ((const float2*)v)[dd.w];
    float b0 = bc[0], b1 = bc[1];
    float4 r0, r1;
    r0.x = u0.x + v0.x + b0;  r0.y = u0.y + v0.y + b1;
    r0.z = u1.x + v1.x + b0;  r0.w = u1.y + v1.y + b1;
    r1.x = u2.x + v2.x + b0;  r1.y = u2.y + v2.y + b1;
    r1.z = u3.x + v3.x + b0;  r1.w = u3.y + v3.y + b1;
    ((float4*)out)[2 * i + 0] = r0;
    ((float4*)out)[2 * i + 1] = r1;
}

extern "C" void kernel_launch(void* const* d_in, const int* in_sizes, int n_in,
                              void* d_out, int out_size, void* d_ws, size_t ws_size,
                              hipStream_t stream) {
    const float* x   = (const float*)d_in[0];
    const int*   ei  = (const int*)d_in[1];
    const int*   nei = (const int*)d_in[2];
    const float* W   = (const float*)d_in[3];
    const float* b   = (const float*)d_in[4];
    const float* Wc  = (const float*)d_in[5];
    const float* bc  = (const float*)d_in[6];
    float* out = (float*)d_out;

    const int N = in_sizes[0] / IN_CH;        // 100000
    const int E = in_sizes[1] / 2;            // 1600000
    const int nbkt = (N + BKT_MSK) >> BKT_SH; // 196
    const int nBin = (E + BINCHUNK - 1) / BINCHUNK;  // 391
    const int nG   = (N + 255) / 256;                // 391

    char* ws = (char*)d_ws;
    size_t off = 0;
    unsigned short* hs = (unsigned short*)(ws + off); off += ((size_t)N + 1) * OUT_CH * 2; // 12.8 MB + dummy row
    unsigned* binned = (unsigned*)(ws + off); off += (size_t)MAXBKT * CAPB * 4;            // 9.4 MB
    int*      rows   = (int*)(ws + off);      off += (size_t)MAXBKT * CAPB_PAD * 4;        // 17.3 MB
    unsigned* offs   = (unsigned*)(ws + off); off += (size_t)N * 4;
    unsigned* degP   = (unsigned*)(ws + off); off += (size_t)N * 4;
    float*    dinv   = (float*)(ws + off);    off += (size_t)N * 4;
    float*    u      = (float*)(ws + off);    off += (size_t)N * 2 * 4;
    float*    v      = (float*)(ws + off);    off += (size_t)N * 2 * 4;
    unsigned* bucketCount = (unsigned*)(ws + off); off += (size_t)MAXBKT * 4;

    k_zero_cnt<<<1, 256, 0, stream>>>(bucketCount, MAXBKT);
    k_AG<<<nBin + nG, 1024, 0, stream>>>(x, W, ei, bucketCount, binned, hs, N, E, nbkt, nBin);
    k_csrB<<<nbkt, 1024, 0, stream>>>(binned, bucketCount, rows, offs, degP, dinv, hs, N, nbkt);
    k_gather<<<(N + 3) / 4, 256, 0, stream>>>(offs, degP, rows, (const unsigned*)hs, dinv, b, Wc, u, v, N);
    k_edges<<<(E / 2 + 255) / 256, 256, 0, stream>>>(ei, nei, u, v, bc, out, E);
}

// Round 21
// 129.648 us; speedup vs baseline: 1.1993x; 1.0147x over previous
//
#include <hip/hip_runtime.h>

#define IN_CH 128
#define OUT_CH 64
#define MAXBKT 256      // 512 nodes per bucket -> supports N <= 131072
#define BKT_SH 9
#define BKT_MSK 511
#define CAPB   9216     // per-bucket true-edge capacity (avg 8192 @ E=1.6M, 11-sigma margin)
#define CAPB_PAD 16896  // padded stride: CAPB + 512 nodes * 15 max pad
#define BINCHUNK 4096   // edges per binning block (1024 thr x 4 edges)

typedef __attribute__((ext_vector_type(8))) short short8v;   // 8 bf16 (4 VGPRs)
typedef __attribute__((ext_vector_type(4))) float float4v;   // 4 fp32 acc

union Pack { short8v s8; unsigned u[4]; };

__device__ __forceinline__ unsigned short f2bf(float f) {   // RNE float->bf16
    unsigned u = __float_as_uint(f);
    return (unsigned short)((u + 0x7fffu + ((u >> 16) & 1u)) >> 16);
}
__device__ __forceinline__ unsigned pk2(float a, float b) { // two bf16 in a dword (a=lo)
    return ((unsigned)f2bf(b) << 16) | (unsigned)f2bf(a);
}
__device__ __forceinline__ float bflo(unsigned d) { return __uint_as_float(d << 16); }
__device__ __forceinline__ float bfhi(unsigned d) { return __uint_as_float(d & 0xffff0000u); }

// ============ Pass A (fused with GEMM): per-block histograms -> cnts[k][b]; NO global atomics ====
__global__ __launch_bounds__(1024) void k_prepA(const float* __restrict__ x,
                                                const float* __restrict__ W,
                                                const int* __restrict__ ei,
                                                unsigned* __restrict__ cnts,
                                                unsigned short* __restrict__ hs,
                                                int N, int E, int nbkt, int nBin) {
    __shared__ float smem[IN_CH * 66];   // 33.8 KB, aliased by both paths
    int tid = threadIdx.x;

    if (blockIdx.x < nBin) {
        // ---------------- histogram path ----------------
        unsigned* hist = (unsigned*)smem;          // [MAXBKT]
        int start = blockIdx.x * BINCHUNK;
        int cnt = E - start; if (cnt > BINCHUNK) cnt = BINCHUNK;
        int i0 = tid * 4;

        if (tid < MAXBKT) hist[tid] = 0u;
        __syncthreads();

        if (i0 < cnt) {
            if (i0 + 4 <= cnt) {
                int4 c = ((const int4*)(ei + E + start))[tid];
                atomicAdd(&hist[c.x >> BKT_SH], 1u);
                atomicAdd(&hist[c.y >> BKT_SH], 1u);
                atomicAdd(&hist[c.z >> BKT_SH], 1u);
                atomicAdd(&hist[c.w >> BKT_SH], 1u);
            } else {
                for (int k = i0; k < cnt; ++k)
                    atomicAdd(&hist[ei[E + start + k] >> BKT_SH], 1u);
            }
        }
        __syncthreads();

        if (tid < nbkt)
            cnts[(size_t)tid * nBin + blockIdx.x] = hist[tid];   // plain store, no atomic
    } else {
        // ---------------- gemm path: 256 rows per block (16 waves), hs UNSCALED ----------------
        int chunk = blockIdx.x - nBin;
        int wid = tid >> 6;    // 0..15
        int l   = tid & 63;
        int g   = l >> 4;
        int m   = l & 15;

        if (chunk == 0 && tid < 32)   // zero the dummy row hs[N] (gather pad target)
            ((unsigned*)hs)[((size_t)N << 5) + tid] = 0u;

        float* Wl = smem;             // [128][66], stride 66 breaks bank alias
        const float4* W4 = (const float4*)W;
#pragma unroll
        for (int j = 0; j < 2; ++j) {
            int i4 = tid + j * 1024;  // over 2048 float4
            float4 w = W4[i4];
            int i = i4 * 4;
            int k = i >> 6, c = i & 63;
            float* dst = Wl + k * 66 + c;
            dst[0] = w.x; dst[1] = w.y; dst[2] = w.z; dst[3] = w.w;
        }
        __syncthreads();

        short8v bf[4][4];
#pragma unroll
        for (int s = 0; s < 4; ++s)
#pragma unroll
            for (int t = 0; t < 4; ++t) {
                Pack p;
#pragma unroll
                for (int jj = 0; jj < 4; ++jj) {
                    int k = s * 32 + g * 8 + 2 * jj;
                    float f0 = Wl[(k + 0) * 66 + t * 16 + m];
                    float f1 = Wl[(k + 1) * 66 + t * 16 + m];
                    p.u[jj] = pk2(f0, f1);
                }
                bf[s][t] = p.s8;
            }

        int R0 = chunk * 256 + wid * 16;
        int rowA = R0 + m; if (rowA > N - 1) rowA = N - 1;
        float4v acc[4];
#pragma unroll
        for (int t = 0; t < 4; ++t) acc[t] = (float4v){0.f, 0.f, 0.f, 0.f};

        const float4* x4 = (const float4*)x;
#pragma unroll
        for (int s = 0; s < 4; ++s) {
            const float4* ap = x4 + (size_t)rowA * 32 + s * 8 + g * 2;
            float4 a0 = ap[0];
            float4 a1 = ap[1];
            Pack pa;
            pa.u[0] = pk2(a0.x, a0.y);
            pa.u[1] = pk2(a0.z, a0.w);
            pa.u[2] = pk2(a1.x, a1.y);
            pa.u[3] = pk2(a1.z, a1.w);
#pragma unroll
            for (int t = 0; t < 4; ++t)
                acc[t] = __builtin_amdgcn_mfma_f32_16x16x32_bf16(pa.s8, bf[s][t], acc[t], 0, 0, 0);
        }

        int rbase = R0 + g * 4;
#pragma unroll
        for (int r = 0; r < 4; ++r) {
            int row = rbase + r;
            if (row < N) {
#pragma unroll
                for (int t = 0; t < 4; ++t)
                    hs[(size_t)row * OUT_CH + t * 16 + m] = f2bf(acc[t][r]);
            }
        }
    }
}

// ============ Scan: per-bucket exclusive scan of block counts; writes bucket totals ============
__global__ __launch_bounds__(512) void k_scan(unsigned* __restrict__ cnts,
                                              unsigned* __restrict__ bucketCount,
                                              int nBin, int nbkt) {
    __shared__ unsigned wsum[8];
    __shared__ unsigned wexc[8];
    int tid = threadIdx.x;
    int k = blockIdx.x;
    unsigned v = (tid < nBin) ? cnts[(size_t)k * nBin + tid] : 0u;
    unsigned inc = v;
#pragma unroll
    for (int o = 1; o < 64; o <<= 1) {
        unsigned t = __shfl_up(inc, o);
        if ((tid & 63) >= o) inc += t;
    }
    if ((tid & 63) == 63) wsum[tid >> 6] = inc;
    __syncthreads();
    if (tid < 8) {
        unsigned s = wsum[tid];
        unsigned i2 = s;
#pragma unroll
        for (int o = 1; o < 8; o <<= 1) {
            unsigned t = __shfl_up(i2, o);
            if (tid >= o) i2 += t;
        }
        wexc[tid] = i2 - s;
    }
    __syncthreads();
    unsigned excl = wexc[tid >> 6] + inc - v;
    if (tid < nBin) cnts[(size_t)k * nBin + tid] = excl;   // in-place exclusive bases
    if (tid == nBin - 1) bucketCount[k] = excl + v;        // bucket total
}

// ============ Pass C: scatter with deterministic bases + local LDS ranks; NO global atomics ====
__global__ __launch_bounds__(1024) void k_binC(const int* __restrict__ ei,
                                               const unsigned* __restrict__ cnts,
                                               unsigned* __restrict__ binned,
                                               int E, int nbkt, int nBin) {
    __shared__ unsigned hist[MAXBKT];
    __shared__ unsigned base_l[MAXBKT];
    int tid = threadIdx.x;
    int start = blockIdx.x * BINCHUNK;
    int cnt = E - start; if (cnt > BINCHUNK) cnt = BINCHUNK;
    int i0 = tid * 4;

    if (tid < MAXBKT) {
        hist[tid] = 0u;
        base_l[tid] = (tid < nbkt) ? cnts[(size_t)tid * nBin + blockIdx.x] : 0u;
    }
    __syncthreads();

    if (i0 < cnt) {
        if (i0 + 4 <= cnt) {
            int4 c = ((const int4*)(ei + E + start))[tid];
            int4 r = ((const int4*)(ei + start))[tid];
            int cc[4] = {c.x, c.y, c.z, c.w};
            int rr[4] = {r.x, r.y, r.z, r.w};
#pragma unroll
            for (int k = 0; k < 4; ++k) {
                int bkt = cc[k] >> BKT_SH;
                unsigned rank = atomicAdd(&hist[bkt], 1u);   // LDS only
                unsigned idx = base_l[bkt] + rank;
                if (idx < CAPB)
                    binned[(size_t)bkt * CAPB + idx] =
                        ((unsigned)rr[k] << BKT_SH) | (unsigned)(cc[k] & BKT_MSK);
            }
        } else {
            for (int k = i0; k < cnt; ++k) {
                int c = ei[E + start + k];
                int r = ei[start + k];
                int bkt = c >> BKT_SH;
                unsigned rank = atomicAdd(&hist[bkt], 1u);
                unsigned idx = base_l[bkt] + rank;
                if (idx < CAPB)
                    binned[(size_t)bkt * CAPB + idx] =
                        ((unsigned)r << BKT_SH) | (unsigned)(c & BKT_MSK);
            }
        }
    }
}

// ---------------- Phase B: padded CSR build + hs dinv-scaling post-pass ----------------
__global__ __launch_bounds__(1024) void k_csrB(const unsigned* __restrict__ binned,
                                               const unsigned* __restrict__ bucketCount,
                                               int* __restrict__ rows,
                                               unsigned* __restrict__ offs,
                                               unsigned* __restrict__ degPad,
                                               float* __restrict__ dinv,
                                               unsigned short* __restrict__ hs,
                                               int N, int nbkt) {
    __shared__ unsigned hist[512];
    __shared__ unsigned degS[512];
    __shared__ unsigned excl[512];
    __shared__ unsigned wsum[8];
    __shared__ unsigned wexc[8];
    __shared__ unsigned stage[CAPB];   // 36 KB
    int tid = threadIdx.x;
    int b = blockIdx.x;
    unsigned cnt = bucketCount[b];
    if (cnt > (unsigned)CAPB) cnt = (unsigned)CAPB;
    size_t gbase = (size_t)b * CAPB_PAD;
    int nodeBase = b << BKT_SH;
    int nn = N - nodeBase; if (nn > 512) nn = 512;

    for (int i = tid; i < 512; i += 1024) hist[i] = 0u;
    __syncthreads();                                   // B1

    const unsigned* src = binned + (size_t)b * CAPB;
    for (unsigned i = tid; i < cnt; i += 1024) {
        unsigned p = src[i];
        stage[i] = p;
        atomicAdd(&hist[p & BKT_MSK], 1u);
    }
    __syncthreads();                                   // B2

    unsigned d = 0, dp = 0, winc = 0;
    if (tid < 512) {
        d = hist[tid];
        degS[tid] = d;                                 // save true degree
        dp = (d + 15u) & ~15u;
        winc = dp;
#pragma unroll
        for (int o = 1; o < 64; o <<= 1) {
            unsigned t = __shfl_up(winc, o);
            if ((tid & 63) >= o) winc += t;
        }
        if ((tid & 63) == 63) wsum[tid >> 6] = winc;
    }
    __syncthreads();                                   // B3
    if (tid < 8) {
        unsigned s = wsum[tid];
        unsigned inc = s;
#pragma unroll
        for (int o = 1; o < 8; o <<= 1) {
            unsigned t = __shfl_up(inc, o);
            if (tid >= o) inc += t;
        }
        wexc[tid] = inc - s;
    }
    __syncthreads();                                   // B4
    if (tid < 512) excl[tid] = wexc[tid >> 6] + winc - dp;
    __syncthreads();                                   // B5

    if (tid < nn) {
        offs[nodeBase + tid]   = (unsigned)gbase + excl[tid];
        degPad[nodeBase + tid] = dp;
        dinv[nodeBase + tid]   = rsqrtf((float)d + 1.0f);
    }

    // reverse-rank scatter: first writer gets slot d-1, last gets 0
    for (unsigned i = tid; i < cnt; i += 1024) {
        unsigned p = stage[i];
        unsigned c = p & BKT_MSK;
        unsigned r = atomicAdd(&hist[c], 0xFFFFFFFFu);   // returns old count
        rows[gbase + excl[c] + r - 1u] = (int)(p >> BKT_SH);
    }
    // pad fill [d, dp): disjoint from scatter range [0, d)
    if (tid < nn) {
        size_t base = gbase + excl[tid];
        for (unsigned p = d; p < dp; ++p) rows[base + p] = N;
    }

    // ---- post-pass: hs[row] *= dinv(row) for this bucket's rows (2 threads/row) ----
    int node_l = tid >> 1;
    if (node_l < nn) {
        float dv = rsqrtf((float)degS[node_l] + 1.0f);
        uint4* hq = (uint4*)hs;
        size_t base = ((size_t)(nodeBase + node_l) << 3) + ((size_t)(tid & 1) << 2);
#pragma unroll
        for (int q = 0; q < 4; ++q) {
            uint4 w = hq[base + q];
            w.x = pk2(bflo(w.x) * dv, bfhi(w.x) * dv);
            w.y = pk2(bflo(w.y) * dv, bfhi(w.y) * dv);
            w.z = pk2(bflo(w.z) * dv, bfhi(w.z) * dv);
            w.w = pk2(bflo(w.w) * dv, bfhi(w.w) * dv);
            hq[base + q] = w;
        }
    }
}

// ---------------- wave-per-node gather: padded lists, mask-free 8-deep rounds ----------------
__global__ __launch_bounds__(256) void k_gather(const unsigned* __restrict__ offs,
                                                const unsigned* __restrict__ degPad,
                                                const int* __restrict__ rows,
                                                const unsigned* __restrict__ hsd,
                                                const float* __restrict__ dinv,
                                                const float* __restrict__ b,
                                                const float* __restrict__ Wc,
                                                float* __restrict__ u,
                                                float* __restrict__ v, int n) {
    int lane = threadIdx.x & 63;
    int half = lane >> 5;          // 0 or 1
    int l32  = lane & 31;
    int node = blockIdx.x * (blockDim.x >> 6) + (threadIdx.x >> 6);
    if (node >= n) return;
    unsigned start = offs[node];
    unsigned cntP = degPad[node];              // multiple of 16 (possibly 0)
    const int* rp = rows + start;

    unsigned ds = hsd[((size_t)node << 5) + l32];
    float acc0 = half ? 0.f : bflo(ds);        // self-loop: half 0 only
    float acc1 = half ? 0.f : bfhi(ds);

    for (unsigned j0 = 0; j0 < cntP; j0 += 64) {
        unsigned rem = cntP - j0;
        unsigned np = rem < 64u ? rem : 64u;   // multiple of 16, wave-uniform
        int myidx = rp[j0 + (lane < (int)np ? lane : 0)];   // one coalesced load / window

        for (unsigned t0 = 0; t0 < np; t0 += 16) {   // 16 edges, 8 gathers in flight / half
            int rr[8];
#pragma unroll
            for (int s = 0; s < 8; ++s)
                rr[s] = __shfl(myidx, (int)t0 + 2 * s + half);
            unsigned dd[8];
#pragma unroll
            for (int s = 0; s < 8; ++s)
                dd[s] = hsd[((size_t)rr[s] << 5) + l32];
#pragma unroll
            for (int s = 0; s < 8; ++s) {
                acc0 += bflo(dd[s]);
                acc1 += bfhi(dd[s]);
            }
        }
    }

    acc0 += __shfl_xor(acc0, 32);              // both halves now hold the full sums
    acc1 += __shfl_xor(acc1, 32);

    float di = dinv[node];
    float2 bv = ((const float2*)b)[l32];
    float z0 = fmaxf(fmaf(acc0, di, bv.x), 0.f);
    float z1 = fmaxf(fmaf(acc1, di, bv.y), 0.f);

    // split epilogue: half 0 reduces u (Wc[:64]), half 1 reduces v (Wc[64:])
    float4 w = ((const float4*)(Wc + (half ? 128 : 0)))[l32];
    float p0 = z0 * w.x + z1 * w.z;
    float p1 = z0 * w.y + z1 * w.w;
#pragma unroll
    for (int off = 16; off > 0; off >>= 1) {   // xor-butterfly stays within each 32-half
        p0 += __shfl_xor(p0, off);
        p1 += __shfl_xor(p1, off);
    }
    float2 r; r.x = p0; r.y = p1;
    if (lane == 0)  ((float2*)u)[node] = r;
    if (lane == 32) ((float2*)v)[node] = r;
}

// ---------------- out: 4 edges per thread, int4 index loads, 2x float4 stores ----------------
__global__ void k_edges(const int* __restrict__ ei, const int* __restrict__ nei,
                        const float* __restrict__ u, const float* __restrict__ v,
                        const float* __restrict__ bc, float* __restrict__ out, int E) {
    int i = blockIdx.x * blockDim.x + threadIdx.x;   // quad index; E % 4 == 0
    int quads = E >> 1;                              // total quads over pos+neg (2E/4)
    if (i >= quads) return;
    int halfQ = quads >> 1;                          // E/4 pos quads
    const int* base = (i < halfQ) ? ei : nei;
    int pi = (i < halfQ) ? i : i - halfQ;
    int4 ss = ((const int4*)base)[pi];
    int4 dd = ((const int4*)(base + E))[pi];
    float2 u0 = ((const float2*)u)[ss.x];
    float2 u1 = ((const float2*)u)[ss.y];
    float2 u2 = ((const float2*)u)[ss.z];
    float2 u3 = ((const float2*)u)[ss.w];
    float2 v0 = ((const float2*)v)[dd.x];
    float2 v1 = ((const float2*)v)[dd.y];
    float2 v2 = ((const float2*)v)[dd.z];
    float2 v3 = ((const float2*)v)[dd.w];
    float b0 = bc[0], b1 = bc[1];
    float4 r0, r1;
    r0.x = u0.x + v0.x + b0;  r0.y = u0.y + v0.y + b1;
    r0.z = u1.x + v1.x + b0;  r0.w = u1.y + v1.y + b1;
    r1.x = u2.x + v2.x + b0;  r1.y = u2.y + v2.y + b1;
    r1.z = u3.x + v3.x + b0;  r1.w = u3.y + v3.y + b1;
    ((float4*)out)[2 * i + 0] = r0;
    ((float4*)out)[2 * i + 1] = r1;
}

extern "C" void kernel_launch(void* const* d_in, const int* in_sizes, int n_in,
                              void* d_out, int out_size, void* d_ws, size_t ws_size,
                              hipStream_t stream) {
    const float* x   = (const float*)d_in[0];
    const int*   ei  = (const int*)d_in[1];
    const int*   nei = (const int*)d_in[2];
    const float* W   = (const float*)d_in[3];
    const float* b   = (const float*)d_in[4];
    const float* Wc  = (const float*)d_in[5];
    const float* bc  = (const float*)d_in[6];
    float* out = (float*)d_out;

    const int N = in_sizes[0] / IN_CH;        // 100000
    const int E = in_sizes[1] / 2;            // 1600000
    const int nbkt = (N + BKT_MSK) >> BKT_SH; // 196
    const int nBin = (E + BINCHUNK - 1) / BINCHUNK;  // 391
    const int nG   = (N + 255) / 256;                // 391

    char* ws = (char*)d_ws;
    size_t off = 0;
    unsigned short* hs = (unsigned short*)(ws + off); off += ((size_t)N + 1) * OUT_CH * 2; // 12.8 MB + dummy row
    unsigned* binned = (unsigned*)(ws + off); off += (size_t)MAXBKT * CAPB * 4;            // 9.4 MB
    int*      rows   = (int*)(ws + off);      off += (size_t)MAXBKT * CAPB_PAD * 4;        // 17.3 MB
    unsigned* offs   = (unsigned*)(ws + off); off += (size_t)N * 4;
    unsigned* degP   = (unsigned*)(ws + off); off += (size_t)N * 4;
    float*    dinv   = (float*)(ws + off);    off += (size_t)N * 4;
    float*    u      = (float*)(ws + off);    off += (size_t)N * 2 * 4;
    float*    v      = (float*)(ws + off);    off += (size_t)N * 2 * 4;
    unsigned* bucketCount = (unsigned*)(ws + off); off += (size_t)MAXBKT * 4;
    unsigned* cnts   = (unsigned*)(ws + off); off += (size_t)MAXBKT * 512 * 4;             // 512 KB count matrix

    k_prepA<<<nBin + nG, 1024, 0, stream>>>(x, W, ei, cnts, hs, N, E, nbkt, nBin);
    k_scan<<<nbkt, 512, 0, stream>>>(cnts, bucketCount, nBin, nbkt);
    k_binC<<<nBin, 1024, 0, stream>>>(ei, cnts, binned, E, nbkt, nBin);
    k_csrB<<<nbkt, 1024, 0, stream>>>(binned, bucketCount, rows, offs, degP, dinv, hs, N, nbkt);
    k_gather<<<(N + 3) / 4, 256, 0, stream>>>(offs, degP, rows, (const unsigned*)hs, dinv, b, Wc, u, v, N);
    k_edges<<<(E / 2 + 255) / 256, 256, 0, stream>>>(ei, nei, u, v, bc, out, E);
}

// Round 22
// 127.179 us; speedup vs baseline: 1.2225x; 1.0194x over previous
//
#include <hip/hip_runtime.h>

#define IN_CH 128
#define OUT_CH 64
#define MAXBKT 256      // 512 nodes per bucket -> supports N <= 131072
#define BKT_SH 9
#define BKT_MSK 511
#define CAPB   9216     // per-bucket true-edge capacity (avg 8192 @ E=1.6M, 11-sigma margin)
#define CAPB_PAD 12800  // padded stride: CAPB + 512 nodes * 7 max pad (pad-to-8)
#define BINCHUNK 4096   // edges per binning block (1024 thr x 4 edges)

typedef __attribute__((ext_vector_type(8))) short short8v;   // 8 bf16 (4 VGPRs)
typedef __attribute__((ext_vector_type(4))) float float4v;   // 4 fp32 acc

union Pack { short8v s8; unsigned u[4]; };

__device__ __forceinline__ unsigned short f2bf(float f) {   // RNE float->bf16
    unsigned u = __float_as_uint(f);
    return (unsigned short)((u + 0x7fffu + ((u >> 16) & 1u)) >> 16);
}
__device__ __forceinline__ unsigned pk2(float a, float b) { // two bf16 in a dword (a=lo)
    return ((unsigned)f2bf(b) << 16) | (unsigned)f2bf(a);
}
__device__ __forceinline__ float bflo(unsigned d) { return __uint_as_float(d << 16); }
__device__ __forceinline__ float bfhi(unsigned d) { return __uint_as_float(d & 0xffff0000u); }

// ============ Pass A (fused with GEMM): per-block histograms -> cnts[k][b]; NO global atomics ====
__global__ __launch_bounds__(1024) void k_prepA(const float* __restrict__ x,
                                                const float* __restrict__ W,
                                                const int* __restrict__ ei,
                                                unsigned* __restrict__ cnts,
                                                unsigned short* __restrict__ hs,
                                                int N, int E, int nbkt, int nBin) {
    __shared__ float smem[IN_CH * 66];   // 33.8 KB, aliased by both paths
    int tid = threadIdx.x;

    if (blockIdx.x < nBin) {
        // ---------------- histogram path ----------------
        unsigned* hist = (unsigned*)smem;          // [MAXBKT]
        int start = blockIdx.x * BINCHUNK;
        int cnt = E - start; if (cnt > BINCHUNK) cnt = BINCHUNK;
        int i0 = tid * 4;

        if (tid < MAXBKT) hist[tid] = 0u;
        __syncthreads();

        if (i0 < cnt) {
            if (i0 + 4 <= cnt) {
                int4 c = ((const int4*)(ei + E + start))[tid];
                atomicAdd(&hist[c.x >> BKT_SH], 1u);
                atomicAdd(&hist[c.y >> BKT_SH], 1u);
                atomicAdd(&hist[c.z >> BKT_SH], 1u);
                atomicAdd(&hist[c.w >> BKT_SH], 1u);
            } else {
                for (int k = i0; k < cnt; ++k)
                    atomicAdd(&hist[ei[E + start + k] >> BKT_SH], 1u);
            }
        }
        __syncthreads();

        if (tid < nbkt)
            cnts[(size_t)tid * nBin + blockIdx.x] = hist[tid];   // plain store, no atomic
    } else {
        // ---------------- gemm path: 256 rows per block (16 waves), hs UNSCALED ----------------
        int chunk = blockIdx.x - nBin;
        int wid = tid >> 6;    // 0..15
        int l   = tid & 63;
        int g   = l >> 4;
        int m   = l & 15;

        if (chunk == 0 && tid < 32)   // zero the dummy row hs[N] (gather pad target)
            ((unsigned*)hs)[((size_t)N << 5) + tid] = 0u;

        float* Wl = smem;             // [128][66], stride 66 breaks bank alias
        const float4* W4 = (const float4*)W;
#pragma unroll
        for (int j = 0; j < 2; ++j) {
            int i4 = tid + j * 1024;  // over 2048 float4
            float4 w = W4[i4];
            int i = i4 * 4;
            int k = i >> 6, c = i & 63;
            float* dst = Wl + k * 66 + c;
            dst[0] = w.x; dst[1] = w.y; dst[2] = w.z; dst[3] = w.w;
        }
        __syncthreads();

        short8v bf[4][4];
#pragma unroll
        for (int s = 0; s < 4; ++s)
#pragma unroll
            for (int t = 0; t < 4; ++t) {
                Pack p;
#pragma unroll
                for (int jj = 0; jj < 4; ++jj) {
                    int k = s * 32 + g * 8 + 2 * jj;
                    float f0 = Wl[(k + 0) * 66 + t * 16 + m];
                    float f1 = Wl[(k + 1) * 66 + t * 16 + m];
                    p.u[jj] = pk2(f0, f1);
                }
                bf[s][t] = p.s8;
            }

        int R0 = chunk * 256 + wid * 16;
        int rowA = R0 + m; if (rowA > N - 1) rowA = N - 1;
        float4v acc[4];
#pragma unroll
        for (int t = 0; t < 4; ++t) acc[t] = (float4v){0.f, 0.f, 0.f, 0.f};

        const float4* x4 = (const float4*)x;
#pragma unroll
        for (int s = 0; s < 4; ++s) {
            const float4* ap = x4 + (size_t)rowA * 32 + s * 8 + g * 2;
            float4 a0 = ap[0];
            float4 a1 = ap[1];
            Pack pa;
            pa.u[0] = pk2(a0.x, a0.y);
            pa.u[1] = pk2(a0.z, a0.w);
            pa.u[2] = pk2(a1.x, a1.y);
            pa.u[3] = pk2(a1.z, a1.w);
#pragma unroll
            for (int t = 0; t < 4; ++t)
                acc[t] = __builtin_amdgcn_mfma_f32_16x16x32_bf16(pa.s8, bf[s][t], acc[t], 0, 0, 0);
        }

        int rbase = R0 + g * 4;
#pragma unroll
        for (int r = 0; r < 4; ++r) {
            int row = rbase + r;
            if (row < N) {
#pragma unroll
                for (int t = 0; t < 4; ++t)
                    hs[(size_t)row * OUT_CH + t * 16 + m] = f2bf(acc[t][r]);
            }
        }
    }
}

// ============ Scan: per-bucket exclusive scan of block counts; writes bucket totals ============
__global__ __launch_bounds__(512) void k_scan(unsigned* __restrict__ cnts,
                                              unsigned* __restrict__ bucketCount,
                                              int nBin, int nbkt) {
    __shared__ unsigned wsum[8];
    __shared__ unsigned wexc[8];
    int tid = threadIdx.x;
    int k = blockIdx.x;
    unsigned v = (tid < nBin) ? cnts[(size_t)k * nBin + tid] : 0u;
    unsigned inc = v;
#pragma unroll
    for (int o = 1; o < 64; o <<= 1) {
        unsigned t = __shfl_up(inc, o);
        if ((tid & 63) >= o) inc += t;
    }
    if ((tid & 63) == 63) wsum[tid >> 6] = inc;
    __syncthreads();
    if (tid < 8) {
        unsigned s = wsum[tid];
        unsigned i2 = s;
#pragma unroll
        for (int o = 1; o < 8; o <<= 1) {
            unsigned t = __shfl_up(i2, o);
            if (tid >= o) i2 += t;
        }
        wexc[tid] = i2 - s;
    }
    __syncthreads();
    unsigned excl = wexc[tid >> 6] + inc - v;
    if (tid < nBin) cnts[(size_t)k * nBin + tid] = excl;   // in-place exclusive bases
    if (tid == nBin - 1) bucketCount[k] = excl + v;        // bucket total
}

// ============ Pass C: scatter with deterministic bases + local LDS ranks; NO global atomics ====
__global__ __launch_bounds__(1024) void k_binC(const int* __restrict__ ei,
                                               const unsigned* __restrict__ cnts,
                                               unsigned* __restrict__ binned,
                                               int E, int nbkt, int nBin) {
    __shared__ unsigned hist[MAXBKT];
    __shared__ unsigned base_l[MAXBKT];
    int tid = threadIdx.x;
    int start = blockIdx.x * BINCHUNK;
    int cnt = E - start; if (cnt > BINCHUNK) cnt = BINCHUNK;
    int i0 = tid * 4;

    if (tid < MAXBKT) {
        hist[tid] = 0u;
        base_l[tid] = (tid < nbkt) ? cnts[(size_t)tid * nBin + blockIdx.x] : 0u;
    }
    __syncthreads();

    if (i0 < cnt) {
        if (i0 + 4 <= cnt) {
            int4 c = ((const int4*)(ei + E + start))[tid];
            int4 r = ((const int4*)(ei + start))[tid];
            int cc[4] = {c.x, c.y, c.z, c.w};
            int rr[4] = {r.x, r.y, r.z, r.w};
#pragma unroll
            for (int k = 0; k < 4; ++k) {
                int bkt = cc[k] >> BKT_SH;
                unsigned rank = atomicAdd(&hist[bkt], 1u);   // LDS only
                unsigned idx = base_l[bkt] + rank;
                if (idx < CAPB)
                    binned[(size_t)bkt * CAPB + idx] =
                        ((unsigned)rr[k] << BKT_SH) | (unsigned)(cc[k] & BKT_MSK);
            }
        } else {
            for (int k = i0; k < cnt; ++k) {
                int c = ei[E + start + k];
                int r = ei[start + k];
                int bkt = c >> BKT_SH;
                unsigned rank = atomicAdd(&hist[bkt], 1u);
                unsigned idx = base_l[bkt] + rank;
                if (idx < CAPB)
                    binned[(size_t)bkt * CAPB + idx] =
                        ((unsigned)r << BKT_SH) | (unsigned)(c & BKT_MSK);
            }
        }
    }
}

// ---------------- Phase B: padded CSR build (pad-to-8) + hs dinv-scaling post-pass ----------------
__global__ __launch_bounds__(1024) void k_csrB(const unsigned* __restrict__ binned,
                                               const unsigned* __restrict__ bucketCount,
                                               int* __restrict__ rows,
                                               unsigned* __restrict__ offs,
                                               unsigned* __restrict__ degPad,
                                               float* __restrict__ dinv,
                                               unsigned short* __restrict__ hs,
                                               int N, int nbkt) {
    __shared__ unsigned hist[512];
    __shared__ unsigned degS[512];
    __shared__ unsigned excl[512];
    __shared__ unsigned wsum[8];
    __shared__ unsigned wexc[8];
    __shared__ unsigned stage[CAPB];   // 36 KB
    int tid = threadIdx.x;
    int b = blockIdx.x;
    unsigned cnt = bucketCount[b];
    if (cnt > (unsigned)CAPB) cnt = (unsigned)CAPB;
    size_t gbase = (size_t)b * CAPB_PAD;
    int nodeBase = b << BKT_SH;
    int nn = N - nodeBase; if (nn > 512) nn = 512;

    for (int i = tid; i < 512; i += 1024) hist[i] = 0u;
    __syncthreads();                                   // B1

    const unsigned* src = binned + (size_t)b * CAPB;
    for (unsigned i = tid; i < cnt; i += 1024) {
        unsigned p = src[i];
        stage[i] = p;
        atomicAdd(&hist[p & BKT_MSK], 1u);
    }
    __syncthreads();                                   // B2

    unsigned d = 0, dp = 0, winc = 0;
    if (tid < 512) {
        d = hist[tid];
        degS[tid] = d;                                 // save true degree
        dp = (d + 7u) & ~7u;                           // pad-to-8
        winc = dp;
#pragma unroll
        for (int o = 1; o < 64; o <<= 1) {
            unsigned t = __shfl_up(winc, o);
            if ((tid & 63) >= o) winc += t;
        }
        if ((tid & 63) == 63) wsum[tid >> 6] = winc;
    }
    __syncthreads();                                   // B3
    if (tid < 8) {
        unsigned s = wsum[tid];
        unsigned inc = s;
#pragma unroll
        for (int o = 1; o < 8; o <<= 1) {
            unsigned t = __shfl_up(inc, o);
            if (tid >= o) inc += t;
        }
        wexc[tid] = inc - s;
    }
    __syncthreads();                                   // B4
    if (tid < 512) excl[tid] = wexc[tid >> 6] + winc - dp;
    __syncthreads();                                   // B5

    if (tid < nn) {
        offs[nodeBase + tid]   = (unsigned)gbase + excl[tid];
        degPad[nodeBase + tid] = dp;
        dinv[nodeBase + tid]   = rsqrtf((float)d + 1.0f);
    }

    // reverse-rank scatter: first writer gets slot d-1, last gets 0
    for (unsigned i = tid; i < cnt; i += 1024) {
        unsigned p = stage[i];
        unsigned c = p & BKT_MSK;
        unsigned r = atomicAdd(&hist[c], 0xFFFFFFFFu);   // returns old count
        rows[gbase + excl[c] + r - 1u] = (int)(p >> BKT_SH);
    }
    // pad fill [d, dp): disjoint from scatter range [0, d)
    if (tid < nn) {
        size_t base = gbase + excl[tid];
        for (unsigned p = d; p < dp; ++p) rows[base + p] = N;
    }

    // ---- post-pass: hs[row] *= dinv(row) for this bucket's rows (2 threads/row) ----
    int node_l = tid >> 1;
    if (node_l < nn) {
        float dv = rsqrtf((float)degS[node_l] + 1.0f);
        uint4* hq = (uint4*)hs;
        size_t base = ((size_t)(nodeBase + node_l) << 3) + ((size_t)(tid & 1) << 2);
#pragma unroll
        for (int q = 0; q < 4; ++q) {
            uint4 w = hq[base + q];
            w.x = pk2(bflo(w.x) * dv, bfhi(w.x) * dv);
            w.y = pk2(bflo(w.y) * dv, bfhi(w.y) * dv);
            w.z = pk2(bflo(w.z) * dv, bfhi(w.z) * dv);
            w.w = pk2(bflo(w.w) * dv, bfhi(w.w) * dv);
            hq[base + q] = w;
        }
    }
}

// ---------------- wave-per-node gather: pad-8 lists, 16-edge rounds + one 8-edge tail ----------
__global__ __launch_bounds__(256) void k_gather(const unsigned* __restrict__ offs,
                                                const unsigned* __restrict__ degPad,
                                                const int* __restrict__ rows,
                                                const unsigned* __restrict__ hsd,
                                                const float* __restrict__ dinv,
                                                const float* __restrict__ b,
                                                const float* __restrict__ Wc,
                                                float* __restrict__ u,
                                                float* __restrict__ v, int n) {
    int lane = threadIdx.x & 63;
    int half = lane >> 5;          // 0 or 1
    int l32  = lane & 31;
    int node = blockIdx.x * (blockDim.x >> 6) + (threadIdx.x >> 6);
    if (node >= n) return;
    unsigned start = offs[node];
    unsigned cntP = degPad[node];              // multiple of 8 (possibly 0)
    const int* rp = rows + start;

    unsigned ds = hsd[((size_t)node << 5) + l32];
    float acc0 = half ? 0.f : bflo(ds);        // self-loop: half 0 only
    float acc1 = half ? 0.f : bfhi(ds);

    for (unsigned j0 = 0; j0 < cntP; j0 += 64) {
        unsigned rem = cntP - j0;
        unsigned np = rem < 64u ? rem : 64u;   // multiple of 8, wave-uniform
        int myidx = rp[j0 + (lane < (int)np ? lane : 0)];   // one coalesced load / window

        unsigned t0 = 0;
        for (; t0 + 16 <= np; t0 += 16) {      // 16 edges, 8 gathers in flight / half
            int rr[8];
#pragma unroll
            for (int s = 0; s < 8; ++s)
                rr[s] = __shfl(myidx, (int)t0 + 2 * s + half);
            unsigned dd[8];
#pragma unroll
            for (int s = 0; s < 8; ++s)
                dd[s] = hsd[((size_t)rr[s] << 5) + l32];
#pragma unroll
            for (int s = 0; s < 8; ++s) {
                acc0 += bflo(dd[s]);
                acc1 += bfhi(dd[s]);
            }
        }
        if (t0 < np) {                         // 8-edge tail, 4 gathers / half
            int rr[4];
#pragma unroll
            for (int s = 0; s < 4; ++s)
                rr[s] = __shfl(myidx, (int)t0 + 2 * s + half);
            unsigned dd[4];
#pragma unroll
            for (int s = 0; s < 4; ++s)
                dd[s] = hsd[((size_t)rr[s] << 5) + l32];
#pragma unroll
            for (int s = 0; s < 4; ++s) {
                acc0 += bflo(dd[s]);
                acc1 += bfhi(dd[s]);
            }
        }
    }

    acc0 += __shfl_xor(acc0, 32);              // both halves now hold the full sums
    acc1 += __shfl_xor(acc1, 32);

    float di = dinv[node];
    float2 bv = ((const float2*)b)[l32];
    float z0 = fmaxf(fmaf(acc0, di, bv.x), 0.f);
    float z1 = fmaxf(fmaf(acc1, di, bv.y), 0.f);

    // split epilogue: half 0 reduces u (Wc[:64]), half 1 reduces v (Wc[64:])
    float4 w = ((const float4*)(Wc + (half ? 128 : 0)))[l32];
    float p0 = z0 * w.x + z1 * w.z;
    float p1 = z0 * w.y + z1 * w.w;
#pragma unroll
    for (int off = 16; off > 0; off >>= 1) {   // xor-butterfly stays within each 32-half
        p0 += __shfl_xor(p0, off);
        p1 += __shfl_xor(p1, off);
    }
    float2 r; r.x = p0; r.y = p1;
    if (lane == 0)  ((float2*)u)[node] = r;
    if (lane == 32) ((float2*)v)[node] = r;
}

// ---------------- out: 4 edges per thread, int4 index loads, 2x float4 stores ----------------
__global__ void k_edges(const int* __restrict__ ei, const int* __restrict__ nei,
                        const float* __restrict__ u, const float* __restrict__ v,
                        const float* __restrict__ bc, float* __restrict__ out, int E) {
    int i = blockIdx.x * blockDim.x + threadIdx.x;   // quad index; E % 4 == 0
    int quads = E >> 1;                              // total quads over pos+neg (2E/4)
    if (i >= quads) return;
    int halfQ = quads >> 1;                          // E/4 pos quads
    const int* base = (i < halfQ) ? ei : nei;
    int pi = (i < halfQ) ? i : i - halfQ;
    int4 ss = ((const int4*)base)[pi];
    int4 dd = ((const int4*)(base + E))[pi];
    float2 u0 = ((const float2*)u)[ss.x];
    float2 u1 = ((const float2*)u)[ss.y];
    float2 u2 = ((const float2*)u)[ss.z];
    float2 u3 = ((const float2*)u)[ss.w];
    float2 v0 = ((const float2*)v)[dd.x];
    float2 v1 = ((const float2*)v)[dd.y];
    float2 v2 = ((const float2*)v)[dd.z];
    float2 v3 = ((const float2*)v)[dd.w];
    float b0 = bc[0], b1 = bc[1];
    float4 r0, r1;
    r0.x = u0.x + v0.x + b0;  r0.y = u0.y + v0.y + b1;
    r0.z = u1.x + v1.x + b0;  r0.w = u1.y + v1.y + b1;
    r1.x = u2.x + v2.x + b0;  r1.y = u2.y + v2.y + b1;
    r1.z = u3.x + v3.x + b0;  r1.w = u3.y + v3.y + b1;
    ((float4*)out)[2 * i + 0] = r0;
    ((float4*)out)[2 * i + 1] = r1;
}

extern "C" void kernel_launch(void* const* d_in, const int* in_sizes, int n_in,
                              void* d_out, int out_size, void* d_ws, size_t ws_size,
                              hipStream_t stream) {
    const float* x   = (const float*)d_in[0];
    const int*   ei  = (const int*)d_in[1];
    const int*   nei = (const int*)d_in[2];
    const float* W   = (const float*)d_in[3];
    const float* b   = (const float*)d_in[4];
    const float* Wc  = (const float*)d_in[5];
    const float* bc  = (const float*)d_in[6];
    float* out = (float*)d_out;

    const int N = in_sizes[0] / IN_CH;        // 100000
    const int E = in_sizes[1] / 2;            // 1600000
    const int nbkt = (N + BKT_MSK) >> BKT_SH; // 196
    const int nBin = (E + BINCHUNK - 1) / BINCHUNK;  // 391
    const int nG   = (N + 255) / 256;                // 391

    char* ws = (char*)d_ws;
    size_t off = 0;
    unsigned short* hs = (unsigned short*)(ws + off); off += ((size_t)N + 1) * OUT_CH * 2; // 12.8 MB + dummy row
    unsigned* binned = (unsigned*)(ws + off); off += (size_t)MAXBKT * CAPB * 4;            // 9.4 MB
    int*      rows   = (int*)(ws + off);      off += (size_t)MAXBKT * CAPB_PAD * 4;        // 13.1 MB
    unsigned* offs   = (unsigned*)(ws + off); off += (size_t)N * 4;
    unsigned* degP   = (unsigned*)(ws + off); off += (size_t)N * 4;
    float*    dinv   = (float*)(ws + off);    off += (size_t)N * 4;
    float*    u      = (float*)(ws + off);    off += (size_t)N * 2 * 4;
    float*    v      = (float*)(ws + off);    off += (size_t)N * 2 * 4;
    unsigned* bucketCount = (unsigned*)(ws + off); off += (size_t)MAXBKT * 4;
    unsigned* cnts   = (unsigned*)(ws + off); off += (size_t)MAXBKT * 512 * 4;             // 512 KB count matrix

    k_prepA<<<nBin + nG, 1024, 0, stream>>>(x, W, ei, cnts, hs, N, E, nbkt, nBin);
    k_scan<<<nbkt, 512, 0, stream>>>(cnts, bucketCount, nBin, nbkt);
    k_binC<<<nBin, 1024, 0, stream>>>(ei, cnts, binned, E, nbkt, nBin);
    k_csrB<<<nbkt, 1024, 0, stream>>>(binned, bucketCount, rows, offs, degP, dinv, hs, N, nbkt);
    k_gather<<<(N + 3) / 4, 256, 0, stream>>>(offs, degP, rows, (const unsigned*)hs, dinv, b, Wc, u, v, N);
    k_edges<<<(E / 2 + 255) / 256, 256, 0, stream>>>(ei, nei, u, v, bc, out, E);
}